// Round 10
// baseline (142.960 us; speedup 1.0000x reference)
//
#include <hip/hip_runtime.h>

#define HOP 256
#define CUT 513
#define T_FRAMES 1021
#define N_SAMPLES 262144
#define BATCH 16
#define NPAIR 511                 // frame pairs per batch (last pair is lone)
#define NWG (BATCH * NPAIR)       // 8176 one-wave blocks, divisible by 8

// 6-bit bit reversal
__device__ __forceinline__ int bitrev6(int v) {
    return ((v & 1) << 5) | ((v & 2) << 3) | ((v & 4) << 1)
         | ((v & 8) >> 1) | ((v & 16) >> 3) | ((v & 32) >> 5);
}

// complex helpers on (cos,sin) pairs
__device__ __forceinline__ double2 cmul(double2 a, double2 b) {
    return make_double2(a.x * b.x - a.y * b.y, a.y * b.x + a.x * b.y);
}
__device__ __forceinline__ double2 csq(double2 a) {
    return make_double2(a.x * a.x - a.y * a.y, 2.0 * a.x * a.y);
}
// y * conj(w): (yr + i*yi) * (c - i*s)
__device__ __forceinline__ double2 cmulw(double yr, double yi, double2 w) {
    return make_double2(yr * w.x + yi * w.y, yi * w.x - yr * w.y);
}

__global__ __launch_bounds__(64, 6) void stft_fft_kernel(
    const float* __restrict__ x,
    const float* __restrict__ basis,
    float* __restrict__ out)
{
    const int lane = threadIdx.x & 63;

    // XCD-chunked bijective swizzle (NWG % 8 == 0): 1022 consecutive per XCD
    const int task = (blockIdx.x & 7) * (NWG / 8) + (blockIdx.x >> 3);
    const int b  = task / NPAIR;
    const int pr = task - b * NPAIR;
    const int t0 = 2 * pr;
    const bool has_b = (t0 + 1 < T_FRAMES);

    // ---- coalesced load: lane holds samples 64j+lane of the 1280-sample span
    const float* xb = x + (size_t)b * N_SAMPLES + (size_t)t0 * HOP;
    float xv[20];
    #pragma unroll
    for (int j = 0; j < 16; ++j) xv[j] = xb[64 * j + lane];
    #pragma unroll
    for (int j = 16; j < 20; ++j) xv[j] = has_b ? xb[64 * j + lane] : 0.0f;

    // pack 2 real frames as complex (fp64); fp32 imag-Nyquist dots (row 1025)
    double2 z[16];
    float IA = 0.f, IB = 0.f;
    #pragma unroll
    for (int r = 0; r < 16; ++r) {
        int n = 64 * r + lane;
        float wn = basis[n];                  // row 0 == Hann window
        float cn = basis[1025 * 1024 + n];    // imag Nyquist row (tiny)
        z[r] = make_double2((double)wn * (double)xv[r],
                            (double)wn * (double)xv[r + 4]);
        IA += cn * xv[r];
        IB += cn * xv[r + 4];
    }
    #pragma unroll
    for (int off = 32; off > 0; off >>= 1) {
        IA += __shfl_down(IA, off);
        IB += __shfl_down(IB, off);
    }
    const float nyIA = __shfl(IA, 0);
    const float nyIB = __shfl(IB, 0);

    // ---- base twiddle W^lane = (cos,sin)(2*pi*lane/1024), poly, x<=0.3866
    double2 w;
    {
        double xx = (6.2831853071795864769252867665590057684 / 1024.0) * (double)lane;
        double x2 = xx * xx;
        w.x = 1.0 + x2 * (-0.5 + x2 * (1.0/24.0 + x2 * (-1.0/720.0
             + x2 * (1.0/40320.0 + x2 * (-1.0/3628800.0)))));
        w.y = xx * (1.0 + x2 * (-1.0/6.0 + x2 * (1.0/120.0 + x2 * (-1.0/5040.0
             + x2 * (1.0/362880.0 + x2 * (-1.0/39916800.0))))));
    }

    // ---- stage 0: radix-4 DIF, stride 256 (in-lane regs r0+{0,4,8,12})
    {
        const double KC[4] = { 1.0, 0.92387953251128675612818318939679,
                               0.70710678118654752440084436210485,
                               0.38268343236508977172845998403040 };
        const double KS[4] = { 0.0, 0.38268343236508977172845998403040,
                               0.70710678118654752440084436210485,
                               0.92387953251128675612818318939679 };
        #pragma unroll
        for (int r0 = 0; r0 < 4; ++r0) {
            double2 w1 = cmul(make_double2(KC[r0], KS[r0]), w);
            double2 w2 = csq(w1);
            double2 w3 = cmul(w1, w2);
            double2 A = z[r0], B = z[r0 + 4], C = z[r0 + 8], D = z[r0 + 12];
            double t0r = A.x + C.x, t0i = A.y + C.y, t1r = A.x - C.x, t1i = A.y - C.y;
            double t2r = B.x + D.x, t2i = B.y + D.y, t3r = B.x - D.x, t3i = B.y - D.y;
            z[r0]      = make_double2(t0r + t2r, t0i + t2i);
            z[r0 + 4]  = cmulw(t1r + t3i, t1i - t3r, w1);
            z[r0 + 8]  = cmulw(t0r - t2r, t0i - t2i, w2);
            z[r0 + 12] = cmulw(t1r - t3i, t1i + t3r, w3);
        }
    }

    // ---- stage 1: radix-4 DIF, stride 64 (in-lane regs 4g+{0..3})
    double2 w8;
    {
        double2 w4 = csq(csq(w));
        w8 = csq(w4);
        double2 w12 = cmul(w4, w8);
        #pragma unroll
        for (int g = 0; g < 4; ++g) {
            double2 A = z[4*g], B = z[4*g+1], C = z[4*g+2], D = z[4*g+3];
            double t0r = A.x + C.x, t0i = A.y + C.y, t1r = A.x - C.x, t1i = A.y - C.y;
            double t2r = B.x + D.x, t2i = B.y + D.y, t3r = B.x - D.x, t3i = B.y - D.y;
            z[4*g]     = make_double2(t0r + t2r, t0i + t2i);
            z[4*g + 1] = cmulw(t1r + t3i, t1i - t3r, w4);
            z[4*g + 2] = cmulw(t0r - t2r, t0i - t2i, w8);
            z[4*g + 3] = cmulw(t1r - t3i, t1i + t3r, w12);
        }
    }

    // ---- stages 2..7: radix-2 DIF across lanes, h = 32..1, BRANCHLESS:
    // s = sgnD*own + partner  (sgnD = -1 for hi lanes, +1 for lo)
    // then uniform multiply by wEff = hi ? (-1)^m * t : (1,0)
    {
        double2 t = csq(w8);   // W^{16*lane}
        #pragma unroll
        for (int st = 0; st < 6; ++st) {
            const int h = 32 >> st;
            const bool hi = (lane & h) != 0;
            const int sgn = (lane >> (5 - st)) & 1;   // m & 1, m = lane/h
            double wx = sgn ? -t.x : t.x;
            double wy = sgn ? -t.y : t.y;
            wx = hi ? wx : 1.0;
            wy = hi ? wy : 0.0;
            const double sgnD = hi ? -1.0 : 1.0;
            #pragma unroll
            for (int r = 0; r < 16; ++r) {
                double vr = __shfl_xor(z[r].x, h);
                double vi = __shfl_xor(z[r].y, h);
                double sr = sgnD * z[r].x + vr;
                double si = sgnD * z[r].y + vi;
                z[r] = make_double2(sr * wx + si * wy, si * wx - sr * wy);
            }
            if (st < 5) t = csq(t);
        }
    }

    // position (r,lane) holds bin k = 16*bitrev6(lane) + drev4(r).
    // Lane-pair epilogue: both lanes of (laneE, laneE+1) gather laneE's bin
    // data; even lane emits frame A, odd lane emits frame B (branchless).
    const int laneE = lane & ~1;
    const int RlE = bitrev6(laneE);               // < 32
    const int lpA = bitrev6(63 - RlE);
    const int lpB = bitrev6((64 - RlE) & 63);
    const int SIG[16] = {0, 3, 2, 1, 15, 14, 13, 12, 11, 10, 9, 8, 7, 6, 5, 4};
    const bool isA = !(lane & 1);

    float* omag = out + (size_t)b * CUT * T_FRAMES;
    float* oph  = omag + (size_t)BATCH * CUT * T_FRAMES;

    #pragma unroll
    for (int r = 0; r < 16; ++r) {
        const int lp = (r == 0) ? lpB : lpA;
        double ax = __shfl(z[r].x, laneE);
        double ay = __shfl(z[r].y, laneE);
        double px = __shfl(z[SIG[r]].x, lp);
        double py = __shfl(z[SIG[r]].y, lp);
        // A: re=(ax+px)/2, im=(ay-py)/2 ; B: re=(ay+py)/2, im=(px-ax)/2
        double rr = isA ? (ax + px) : (ay + py);
        double ii = isA ? (ay - py) : (px - ax);
        float rf  = (float)(0.5 * rr);
        float iff = (float)(0.5 * ii);
        float mg = sqrtf(rf * rf + iff * iff);
        float ph = atan2f(iff, rf);
        const int rho = ((r & 3) << 2) | (r >> 2);
        const int k = 16 * RlE + rho;
        if (isA | has_b) {
            size_t g = (size_t)k * T_FRAMES + (size_t)(t0 + (lane & 1));
            omag[g] = mg;
            oph[g]  = ph;
        }
    }

    // bin 512 lives at lane 1 (Rl=32), reg 0: real from FFT, imag = exact dot
    if (lane == 1) {
        size_t g = (size_t)512 * T_FRAMES + (size_t)t0;
        float rf = (float)z[0].x;
        omag[g] = sqrtf(rf * rf + nyIA * nyIA);
        oph[g]  = atan2f(nyIA, rf);
        if (has_b) {
            float rf2 = (float)z[0].y;
            omag[g + 1] = sqrtf(rf2 * rf2 + nyIB * nyIB);
            oph[g + 1]  = atan2f(nyIB, rf2);
        }
    }
}

extern "C" void kernel_launch(void* const* d_in, const int* in_sizes, int n_in,
                              void* d_out, int out_size, void* d_ws, size_t ws_size,
                              hipStream_t stream) {
    (void)in_sizes; (void)n_in; (void)d_ws; (void)ws_size; (void)out_size;
    const float* x     = (const float*)d_in[0];
    const float* basis = (const float*)d_in[1];
    float* out = (float*)d_out;
    dim3 grid(NWG);     // 8176 one-wave blocks
    dim3 block(64);
    stft_fft_kernel<<<grid, block, 0, stream>>>(x, basis, out);
}

// Round 11
// 71.220 us; speedup vs baseline: 2.0073x; 2.0073x over previous
//
#include <hip/hip_runtime.h>

#define HOP 256
#define CUT 513
#define T_FRAMES 1021
#define N_SAMPLES 262144
#define BATCH 16
#define NPAIR 511                 // frame pairs per batch (last pair is lone)
#define NWG (BATCH * NPAIR)       // 8176 one-wave blocks, divisible by 8

// 6-bit bit reversal
__device__ __forceinline__ int bitrev6(int v) {
    return ((v & 1) << 5) | ((v & 2) << 3) | ((v & 4) << 1)
         | ((v & 8) >> 1) | ((v & 16) >> 3) | ((v & 32) >> 5);
}

// complex helpers on (cos,sin) pairs
__device__ __forceinline__ double2 cmul(double2 a, double2 b) {
    return make_double2(a.x * b.x - a.y * b.y, a.y * b.x + a.x * b.y);
}
__device__ __forceinline__ double2 csq(double2 a) {
    return make_double2(a.x * a.x - a.y * a.y, 2.0 * a.x * a.y);
}
// y * conj(w): (yr + i*yi) * (c - i*s)
__device__ __forceinline__ double2 cmulw(double yr, double yi, double2 w) {
    return make_double2(yr * w.x + yi * w.y, yi * w.x - yr * w.y);
}

__global__ __launch_bounds__(64, 4) void stft_fft_kernel(
    const float* __restrict__ x,
    const float* __restrict__ basis,
    float* __restrict__ out)
{
    const int lane = threadIdx.x & 63;

    // XCD-chunked bijective swizzle (NWG % 8 == 0): 1022 consecutive per XCD
    const int task = (blockIdx.x & 7) * (NWG / 8) + (blockIdx.x >> 3);
    const int b  = task / NPAIR;
    const int pr = task - b * NPAIR;
    const int t0 = 2 * pr;
    const bool has_b = (t0 + 1 < T_FRAMES);

    // ---- coalesced load: lane holds samples 64j+lane of the 1280-sample span
    const float* xb = x + (size_t)b * N_SAMPLES + (size_t)t0 * HOP;
    float xv[20];
    #pragma unroll
    for (int j = 0; j < 16; ++j) xv[j] = xb[64 * j + lane];
    #pragma unroll
    for (int j = 16; j < 20; ++j) xv[j] = has_b ? xb[64 * j + lane] : 0.0f;

    // pack 2 real frames as complex (fp64); fp32 imag-Nyquist dots (row 1025)
    double2 z[16];
    float IA = 0.f, IB = 0.f;
    #pragma unroll
    for (int r = 0; r < 16; ++r) {
        int n = 64 * r + lane;
        float wn = basis[n];                  // row 0 == Hann window
        float cn = basis[1025 * 1024 + n];    // imag Nyquist row (tiny)
        z[r] = make_double2((double)wn * (double)xv[r],
                            (double)wn * (double)xv[r + 4]);
        IA += cn * xv[r];
        IB += cn * xv[r + 4];
    }
    #pragma unroll
    for (int off = 32; off > 0; off >>= 1) {
        IA += __shfl_down(IA, off);
        IB += __shfl_down(IB, off);
    }
    const float nyIA = __shfl(IA, 0);
    const float nyIB = __shfl(IB, 0);

    // ---- base twiddle W^lane = (cos,sin)(2*pi*lane/1024), poly, x<=0.3866
    double2 w;
    {
        double xx = (6.2831853071795864769252867665590057684 / 1024.0) * (double)lane;
        double x2 = xx * xx;
        w.x = 1.0 + x2 * (-0.5 + x2 * (1.0/24.0 + x2 * (-1.0/720.0
             + x2 * (1.0/40320.0 + x2 * (-1.0/3628800.0)))));
        w.y = xx * (1.0 + x2 * (-1.0/6.0 + x2 * (1.0/120.0 + x2 * (-1.0/5040.0
             + x2 * (1.0/362880.0 + x2 * (-1.0/39916800.0))))));
    }

    // ---- stage 0: radix-4 DIF, stride 256 (in-lane regs r0+{0,4,8,12})
    {
        const double KC[4] = { 1.0, 0.92387953251128675612818318939679,
                               0.70710678118654752440084436210485,
                               0.38268343236508977172845998403040 };
        const double KS[4] = { 0.0, 0.38268343236508977172845998403040,
                               0.70710678118654752440084436210485,
                               0.92387953251128675612818318939679 };
        #pragma unroll
        for (int r0 = 0; r0 < 4; ++r0) {
            double2 w1 = cmul(make_double2(KC[r0], KS[r0]), w);
            double2 w2 = csq(w1);
            double2 w3 = cmul(w1, w2);
            double2 A = z[r0], B = z[r0 + 4], C = z[r0 + 8], D = z[r0 + 12];
            double t0r = A.x + C.x, t0i = A.y + C.y, t1r = A.x - C.x, t1i = A.y - C.y;
            double t2r = B.x + D.x, t2i = B.y + D.y, t3r = B.x - D.x, t3i = B.y - D.y;
            z[r0]      = make_double2(t0r + t2r, t0i + t2i);
            z[r0 + 4]  = cmulw(t1r + t3i, t1i - t3r, w1);
            z[r0 + 8]  = cmulw(t0r - t2r, t0i - t2i, w2);
            z[r0 + 12] = cmulw(t1r - t3i, t1i + t3r, w3);
        }
    }

    // ---- stage 1: radix-4 DIF, stride 64 (in-lane regs 4g+{0..3})
    double2 w8;
    {
        double2 w4 = csq(csq(w));
        w8 = csq(w4);
        double2 w12 = cmul(w4, w8);
        #pragma unroll
        for (int g = 0; g < 4; ++g) {
            double2 A = z[4*g], B = z[4*g+1], C = z[4*g+2], D = z[4*g+3];
            double t0r = A.x + C.x, t0i = A.y + C.y, t1r = A.x - C.x, t1i = A.y - C.y;
            double t2r = B.x + D.x, t2i = B.y + D.y, t3r = B.x - D.x, t3i = B.y - D.y;
            z[4*g]     = make_double2(t0r + t2r, t0i + t2i);
            z[4*g + 1] = cmulw(t1r + t3i, t1i - t3r, w4);
            z[4*g + 2] = cmulw(t0r - t2r, t0i - t2i, w8);
            z[4*g + 3] = cmulw(t1r - t3i, t1i + t3r, w12);
        }
    }

    // ---- stages 2..7: radix-2 DIF across lanes, h = 32..1, BRANCHLESS:
    // s = sgnD*own + partner; uniform multiply by wEff = hi ? (-1)^m t : (1,0)
    {
        double2 t = csq(w8);   // W^{16*lane}
        #pragma unroll
        for (int st = 0; st < 6; ++st) {
            const int h = 32 >> st;
            const bool hi = (lane & h) != 0;
            const int sgn = (lane >> (5 - st)) & 1;   // m & 1, m = lane/h
            double wx = sgn ? -t.x : t.x;
            double wy = sgn ? -t.y : t.y;
            wx = hi ? wx : 1.0;
            wy = hi ? wy : 0.0;
            const double sgnD = hi ? -1.0 : 1.0;
            #pragma unroll
            for (int r = 0; r < 16; ++r) {
                double vr = __shfl_xor(z[r].x, h);
                double vi = __shfl_xor(z[r].y, h);
                double sr = sgnD * z[r].x + vr;
                double si = sgnD * z[r].y + vi;
                z[r] = make_double2(sr * wx + si * wy, si * wx - sr * wy);
            }
            if (st < 5) t = csq(t);
        }
    }

    // position (r,lane) holds bin k = 16*bitrev6(lane) + drev4(r).
    // Lane-pair epilogue: both lanes of (laneE, laneE+1) gather laneE's bin
    // data; even lane emits frame A, odd lane emits frame B (branchless).
    const int laneE = lane & ~1;
    const int RlE = bitrev6(laneE);               // < 32
    const int lpA = bitrev6(63 - RlE);
    const int lpB = bitrev6((64 - RlE) & 63);
    const int SIG[16] = {0, 3, 2, 1, 15, 14, 13, 12, 11, 10, 9, 8, 7, 6, 5, 4};
    const bool isA = !(lane & 1);

    float* omag = out + (size_t)b * CUT * T_FRAMES;
    float* oph  = omag + (size_t)BATCH * CUT * T_FRAMES;

    #pragma unroll
    for (int r = 0; r < 16; ++r) {
        const int lp = (r == 0) ? lpB : lpA;
        double ax = __shfl(z[r].x, laneE);
        double ay = __shfl(z[r].y, laneE);
        double px = __shfl(z[SIG[r]].x, lp);
        double py = __shfl(z[SIG[r]].y, lp);
        // A: re=(ax+px)/2, im=(ay-py)/2 ; B: re=(ay+py)/2, im=(px-ax)/2
        double rr = isA ? (ax + px) : (ay + py);
        double ii = isA ? (ay - py) : (px - ax);
        float rf  = (float)(0.5 * rr);
        float iff = (float)(0.5 * ii);
        float mg = sqrtf(rf * rf + iff * iff);
        float ph = atan2f(iff, rf);
        const int rho = ((r & 3) << 2) | (r >> 2);
        const int k = 16 * RlE + rho;
        if (isA | has_b) {
            size_t g = (size_t)k * T_FRAMES + (size_t)(t0 + (lane & 1));
            omag[g] = mg;
            oph[g]  = ph;
        }
    }

    // bin 512 lives at lane 1 (Rl=32), reg 0: real from FFT, imag = exact dot
    if (lane == 1) {
        size_t g = (size_t)512 * T_FRAMES + (size_t)t0;
        float rf = (float)z[0].x;
        omag[g] = sqrtf(rf * rf + nyIA * nyIA);
        oph[g]  = atan2f(nyIA, rf);
        if (has_b) {
            float rf2 = (float)z[0].y;
            omag[g + 1] = sqrtf(rf2 * rf2 + nyIB * nyIB);
            oph[g + 1]  = atan2f(nyIB, rf2);
        }
    }
}

extern "C" void kernel_launch(void* const* d_in, const int* in_sizes, int n_in,
                              void* d_out, int out_size, void* d_ws, size_t ws_size,
                              hipStream_t stream) {
    (void)in_sizes; (void)n_in; (void)d_ws; (void)ws_size; (void)out_size;
    const float* x     = (const float*)d_in[0];
    const float* basis = (const float*)d_in[1];
    float* out = (float*)d_out;
    dim3 grid(NWG);     // 8176 one-wave blocks
    dim3 block(64);
    stft_fft_kernel<<<grid, block, 0, stream>>>(x, basis, out);
}

// Round 12
// 61.059 us; speedup vs baseline: 2.3413x; 1.1664x over previous
//
#include <hip/hip_runtime.h>

#define HOP 256
#define CUT 513
#define T_FRAMES 1021
#define N_SAMPLES 262144
#define BATCH 16
#define NPAIR 511                 // frame pairs per batch (last pair is lone)
#define NWG 2044                  // 8176 wave-tasks / 4 waves per block

// 6-bit bit reversal
__device__ __forceinline__ int bitrev6(int v) {
    return ((v & 1) << 5) | ((v & 2) << 3) | ((v & 4) << 1)
         | ((v & 8) >> 1) | ((v & 16) >> 3) | ((v & 32) >> 5);
}

// complex helpers on (cos,sin) pairs
__device__ __forceinline__ double2 cmul(double2 a, double2 b) {
    return make_double2(a.x * b.x - a.y * b.y, a.y * b.x + a.x * b.y);
}
__device__ __forceinline__ double2 csq(double2 a) {
    return make_double2(a.x * a.x - a.y * a.y, 2.0 * a.x * a.y);
}
// y * conj(w): (yr + i*yi) * (c - i*s)
__device__ __forceinline__ double2 cmulw(double yr, double yi, double2 w) {
    return make_double2(yr * w.x + yi * w.y, yi * w.x - yr * w.y);
}

__global__ __launch_bounds__(256, 3) void stft_fft_kernel(
    const float* __restrict__ x,
    const float* __restrict__ basis,
    float* __restrict__ out)
{
    const int tid  = threadIdx.x;
    const int lane = tid & 63;
    const int wv   = tid >> 6;

    // bijective XCD-chunked swizzle (NWG % 8 == 4); 4 waves of a block take
    // 4 CONSECUTIVE frame-pairs -> each block covers 32 B of every output line
    const int q8 = NWG >> 3, rem = NWG & 7;
    const int xcd = blockIdx.x & 7, idx = blockIdx.x >> 3;
    const int sb = (xcd < rem) ? (xcd * (q8 + 1) + idx)
                               : (rem * (q8 + 1) + (xcd - rem) * q8 + idx);
    const int task = sb * 4 + wv;
    const int b  = task / NPAIR;
    const int pr = task - b * NPAIR;
    const int t0 = 2 * pr;
    const bool has_b = (t0 + 1 < T_FRAMES);

    // ---- coalesced load: lane holds samples 64j+lane of the 1280-sample span
    const float* xb = x + (size_t)b * N_SAMPLES + (size_t)t0 * HOP;
    float xv[20];
    #pragma unroll
    for (int j = 0; j < 16; ++j) xv[j] = xb[64 * j + lane];
    #pragma unroll
    for (int j = 16; j < 20; ++j) xv[j] = has_b ? xb[64 * j + lane] : 0.0f;

    // pack 2 real frames as complex (fp64); fp32 imag-Nyquist dots (row 1025)
    double2 z[16];
    float IA = 0.f, IB = 0.f;
    #pragma unroll
    for (int r = 0; r < 16; ++r) {
        int n = 64 * r + lane;
        float wn = basis[n];                  // row 0 == Hann window
        float cn = basis[1025 * 1024 + n];    // imag Nyquist row (tiny)
        z[r] = make_double2((double)wn * (double)xv[r],
                            (double)wn * (double)xv[r + 4]);
        IA += cn * xv[r];
        IB += cn * xv[r + 4];
    }
    #pragma unroll
    for (int off = 32; off > 0; off >>= 1) {
        IA += __shfl_down(IA, off);
        IB += __shfl_down(IB, off);
    }
    const float nyIA = __shfl(IA, 0);
    const float nyIB = __shfl(IB, 0);

    // ---- base twiddle W^lane = (cos,sin)(2*pi*lane/1024), poly, x<=0.3866
    double2 w;
    {
        double xx = (6.2831853071795864769252867665590057684 / 1024.0) * (double)lane;
        double x2 = xx * xx;
        w.x = 1.0 + x2 * (-0.5 + x2 * (1.0/24.0 + x2 * (-1.0/720.0
             + x2 * (1.0/40320.0 + x2 * (-1.0/3628800.0)))));
        w.y = xx * (1.0 + x2 * (-1.0/6.0 + x2 * (1.0/120.0 + x2 * (-1.0/5040.0
             + x2 * (1.0/362880.0 + x2 * (-1.0/39916800.0))))));
    }

    // ---- stage 0: radix-4 DIF, stride 256 (in-lane regs r0+{0,4,8,12})
    {
        const double KC[4] = { 1.0, 0.92387953251128675612818318939679,
                               0.70710678118654752440084436210485,
                               0.38268343236508977172845998403040 };
        const double KS[4] = { 0.0, 0.38268343236508977172845998403040,
                               0.70710678118654752440084436210485,
                               0.92387953251128675612818318939679 };
        #pragma unroll
        for (int r0 = 0; r0 < 4; ++r0) {
            double2 w1 = cmul(make_double2(KC[r0], KS[r0]), w);
            double2 w2 = csq(w1);
            double2 w3 = cmul(w1, w2);
            double2 A = z[r0], B = z[r0 + 4], C = z[r0 + 8], D = z[r0 + 12];
            double t0r = A.x + C.x, t0i = A.y + C.y, t1r = A.x - C.x, t1i = A.y - C.y;
            double t2r = B.x + D.x, t2i = B.y + D.y, t3r = B.x - D.x, t3i = B.y - D.y;
            z[r0]      = make_double2(t0r + t2r, t0i + t2i);
            z[r0 + 4]  = cmulw(t1r + t3i, t1i - t3r, w1);
            z[r0 + 8]  = cmulw(t0r - t2r, t0i - t2i, w2);
            z[r0 + 12] = cmulw(t1r - t3i, t1i + t3r, w3);
        }
    }

    // ---- stage 1: radix-4 DIF, stride 64 (in-lane regs 4g+{0..3})
    double2 w8;
    {
        double2 w4 = csq(csq(w));
        w8 = csq(w4);
        double2 w12 = cmul(w4, w8);
        #pragma unroll
        for (int g = 0; g < 4; ++g) {
            double2 A = z[4*g], B = z[4*g+1], C = z[4*g+2], D = z[4*g+3];
            double t0r = A.x + C.x, t0i = A.y + C.y, t1r = A.x - C.x, t1i = A.y - C.y;
            double t2r = B.x + D.x, t2i = B.y + D.y, t3r = B.x - D.x, t3i = B.y - D.y;
            z[4*g]     = make_double2(t0r + t2r, t0i + t2i);
            z[4*g + 1] = cmulw(t1r + t3i, t1i - t3r, w4);
            z[4*g + 2] = cmulw(t0r - t2r, t0i - t2i, w8);
            z[4*g + 3] = cmulw(t1r - t3i, t1i + t3r, w12);
        }
    }

    // ---- stages 2..7: radix-2 DIF across lanes, h = 32..1, BRANCHLESS:
    // s = sgnD*own + partner; uniform multiply by wEff = hi ? (-1)^m t : (1,0)
    {
        double2 t = csq(w8);   // W^{16*lane}
        #pragma unroll
        for (int st = 0; st < 6; ++st) {
            const int h = 32 >> st;
            const bool hi = (lane & h) != 0;
            const int sgn = (lane >> (5 - st)) & 1;   // m & 1, m = lane/h
            double wx = sgn ? -t.x : t.x;
            double wy = sgn ? -t.y : t.y;
            wx = hi ? wx : 1.0;
            wy = hi ? wy : 0.0;
            const double sgnD = hi ? -1.0 : 1.0;
            #pragma unroll
            for (int r = 0; r < 16; ++r) {
                double vr = __shfl_xor(z[r].x, h);
                double vi = __shfl_xor(z[r].y, h);
                double sr = sgnD * z[r].x + vr;
                double si = sgnD * z[r].y + vi;
                z[r] = make_double2(sr * wx + si * wy, si * wx - sr * wy);
            }
            if (st < 5) t = csq(t);
        }
    }

    // position (r,lane) holds bin k = 16*bitrev6(lane) + drev4(r).
    // Lane-pair epilogue: both lanes of (laneE, laneE+1) gather laneE's bin
    // data; even lane emits frame A, odd lane emits frame B (branchless).
    const int laneE = lane & ~1;
    const int RlE = bitrev6(laneE);               // < 32
    const int lpA = bitrev6(63 - RlE);
    const int lpB = bitrev6((64 - RlE) & 63);
    const int SIG[16] = {0, 3, 2, 1, 15, 14, 13, 12, 11, 10, 9, 8, 7, 6, 5, 4};
    const bool isA = !(lane & 1);

    float* omag = out + (size_t)b * CUT * T_FRAMES;
    float* oph  = omag + (size_t)BATCH * CUT * T_FRAMES;

    #pragma unroll
    for (int r = 0; r < 16; ++r) {
        const int lp = (r == 0) ? lpB : lpA;
        double ax = __shfl(z[r].x, laneE);
        double ay = __shfl(z[r].y, laneE);
        double px = __shfl(z[SIG[r]].x, lp);
        double py = __shfl(z[SIG[r]].y, lp);
        // A: re=(ax+px)/2, im=(ay-py)/2 ; B: re=(ay+py)/2, im=(px-ax)/2
        double rr = isA ? (ax + px) : (ay + py);
        double ii = isA ? (ay - py) : (px - ax);
        float rf  = (float)(0.5 * rr);
        float iff = (float)(0.5 * ii);
        float mg = sqrtf(rf * rf + iff * iff);
        float ph = atan2f(iff, rf);
        const int rho = ((r & 3) << 2) | (r >> 2);
        const int k = 16 * RlE + rho;
        if (isA | has_b) {
            size_t g = (size_t)k * T_FRAMES + (size_t)(t0 + (lane & 1));
            omag[g] = mg;
            oph[g]  = ph;
        }
    }

    // bin 512 lives at lane 1 (Rl=32), reg 0: real from FFT, imag = exact dot
    if (lane == 1) {
        size_t g = (size_t)512 * T_FRAMES + (size_t)t0;
        float rf = (float)z[0].x;
        omag[g] = sqrtf(rf * rf + nyIA * nyIA);
        oph[g]  = atan2f(nyIA, rf);
        if (has_b) {
            float rf2 = (float)z[0].y;
            omag[g + 1] = sqrtf(rf2 * rf2 + nyIB * nyIB);
            oph[g + 1]  = atan2f(nyIB, rf2);
        }
    }
}

extern "C" void kernel_launch(void* const* d_in, const int* in_sizes, int n_in,
                              void* d_out, int out_size, void* d_ws, size_t ws_size,
                              hipStream_t stream) {
    (void)in_sizes; (void)n_in; (void)d_ws; (void)ws_size; (void)out_size;
    const float* x     = (const float*)d_in[0];
    const float* basis = (const float*)d_in[1];
    float* out = (float*)d_out;
    dim3 grid(NWG);     // 2044 blocks x 4 waves
    dim3 block(256);
    stft_fft_kernel<<<grid, block, 0, stream>>>(x, basis, out);
}